// Round 9
// baseline (167.985 us; speedup 1.0000x reference)
//
#include <hip/hip_runtime.h>
#include <hip/hip_fp16.h>
#include <stdint.h>

// Problem constants (fixed by setup_inputs)
#define TT 2048
#define BB 64
#define VV 256
#define SS 256
#define LL 513

#define F_L2E 1.4426950408889634f
#define F_LN2 0.6931471805599453f
#define TGT_E 40   // per-lane rescale target: lane max -> [2^40, 2^41)
#define MARG  50   // max allowed C(i-1)-C(i): bounds handoff to 2^(41+MARG)
#define KOFF  262144

static __device__ __forceinline__ float exp2_fast(float x) {
  float r; asm("v_exp_f32 %0, %1" : "=v"(r) : "v"(x)); return r;
}
static __device__ __forceinline__ float log2_fast(float x) {
  float r; asm("v_log_f32 %0, %1" : "=v"(r) : "v"(x)); return r;
}
static __device__ __forceinline__ void g2l16(const void* g, void* l) {
  __builtin_amdgcn_global_load_lds((const __attribute__((address_space(1))) void*)g,
                                   (__attribute__((address_space(3))) void*)l, 16, 0, 0);
}
// wave_shr:1 — lane i gets lane i-1's value; lane 0 gets 0 (bound_ctrl). Pure VALU.
static __device__ __forceinline__ float dpp_shr1_f(float x) {
  int r = __builtin_amdgcn_update_dpp(0, __float_as_int(x), 0x138, 0xF, 0xF, true);
  return __int_as_float(r);
}
static __device__ __forceinline__ int dpp_shr1_i(int x) {
  return __builtin_amdgcn_update_dpp(0, x, 0x138, 0xF, 0xF, true);
}
// One step of wave64 inclusive MAX-scan. Invalid-source lanes keep old (bound_ctrl
// false, old = v). Canonical sequence: shr1,shr2,shr4,shr8 (rmask F) then
// bcast15 (rmask 0xa: rows 1,3 only) and bcast31 (rmask 0xc: rows 2,3 only).
template <int CTRL, int RMASK>
static __device__ __forceinline__ int dppmax_i(int v) {
  int d = __builtin_amdgcn_update_dpp(v, v, CTRL, RMASK, 0xF, false);
  return v > d ? v : d;
}
static __device__ __forceinline__ int scanmax_i(int v) {
  v = dppmax_i<0x111, 0xF>(v);
  v = dppmax_i<0x112, 0xF>(v);
  v = dppmax_i<0x114, 0xF>(v);
  v = dppmax_i<0x118, 0xF>(v);
  v = dppmax_i<0x142, 0xa>(v);
  v = dppmax_i<0x143, 0xc>(v);
  return v;   // inclusive prefix max per lane
}

// ---------------------------------------------------------------------
// Phase 1: fused exp + row-sum + target-gather.
//   Eg[b][t][s]  (fp16) = exp(lp[t][b][tgt[b][s]])   s in [0,256)
//   Bl[b][t]     (f32)  = exp(lp[t][b][0])           blank prob
//   D2T[b][t]    (f32)  = -log2 sum_v exp(lp[t][b][v])
// ---------------------------------------------------------------------
__global__ __launch_bounds__(256) void k_prep2(const float* __restrict__ lp,
                                               const int* __restrict__ tgt,
                                               __half* __restrict__ Eg,
                                               float* __restrict__ Bl,
                                               float* __restrict__ D2T) {
  __shared__ int tgtl[SS];
  __shared__ __half elds[4][VV];
  int b  = blockIdx.x & (BB - 1);
  int t0 = (blockIdx.x >> 6) << 2;
  int tid = threadIdx.x;
  tgtl[tid] = tgt[b * SS + tid];
  __syncthreads();
  int w = tid >> 6, lane = tid & 63;
  int t = t0 + w;
  float4 x = reinterpret_cast<const float4*>(lp + ((size_t)t * BB + b) * VV)[lane];
  float e0 = exp2_fast(x.x * F_L2E), e1 = exp2_fast(x.y * F_L2E);
  float e2 = exp2_fast(x.z * F_L2E), e3 = exp2_fast(x.w * F_L2E);
  float z = (e0 + e1) + (e2 + e3);
  z += __shfl_xor(z, 1);
  z += __shfl_xor(z, 2);
  z += __shfl_xor(z, 4);
  z += __shfl_xor(z, 8);
  z += __shfl_xor(z, 16);
  z += __shfl_xor(z, 32);
  elds[w][4 * lane + 0] = __float2half_rn(e0);
  elds[w][4 * lane + 1] = __float2half_rn(e1);
  elds[w][4 * lane + 2] = __float2half_rn(e2);
  elds[w][4 * lane + 3] = __float2half_rn(e3);
  asm volatile("s_waitcnt lgkmcnt(0)" ::: "memory");   // wave-local write->read
  int s = 4 * lane;
  union { __half h[4]; uint2 u; } pk;
  pk.h[0] = elds[w][tgtl[s + 0]];
  pk.h[1] = elds[w][tgtl[s + 1]];
  pk.h[2] = elds[w][tgtl[s + 2]];
  pk.h[3] = elds[w][tgtl[s + 3]];
  reinterpret_cast<uint2*>(Eg + ((size_t)b * TT + t) * SS)[lane] = pk.u;
  if (lane == 0) {
    Bl[(size_t)b * TT + t]  = e0;
    D2T[(size_t)b * TT + t] = -log2_fast(z);
  }
}

// ---------------------------------------------------------------------
// Phase 2: f32 CTC DP with PER-LANE block exponent, margin-clamped.
// alpha_true(cell of lane i) = a * 2^C(i).  Every 8 steps:
//   Cl_i = frame putting own max at 2^TGT_E (live lanes)
//   P_i  = inclusive prefix max over live lanes' Cl
//   C_i  = live ? max(Cl_i, P_i - MARG) : (P_i - MARG)
// => C(i-1)-C(i) <= MARG always; handoff h1 = a7(i-1)*2^{C(i-1)-C(i)}
// bounded by 2^{41+MARG} (no overflow). Dead/front lanes sit in a frame
// at most MARG bits below the local prefix max (no propagation lag).
// ---------------------------------------------------------------------
__global__ __launch_bounds__(64) void k_ctc6(const __half* __restrict__ Eg,
                                             const float* __restrict__ Bl,
                                             const int* __restrict__ tgt,
                                             const int* __restrict__ ilen,
                                             const int* __restrict__ tlen,
                                             const float* __restrict__ D2T,
                                             float* __restrict__ lossw) {
  __shared__ float blanklds[TT];   // 8 KB
  __shared__ float afin[LL];
  __shared__ int   cfinl[64];
  int b = blockIdx.x, lane = threadIdx.x;
  int len = ilen[b]; if (len > TT) len = TT; if (len < 0) len = 0;
  int tl  = tlen[b]; if (tl > SS) tl = SS; if (tl < 1) tl = 1;

  const float* blb = Bl  + (size_t)b * TT;
  const float* d2b = D2T + (size_t)b * TT;
  const uint2* eq  = reinterpret_cast<const uint2*>(Eg) + (size_t)b * TT * 64 + lane;

  int4 tv = reinterpret_cast<const int4*>(tgt + b * SS)[lane];
  int pw  = __shfl_up(tv.w, 1);
  float mk1 = (lane > 0 && tv.x != pw) ? 1.f : 0.f;
  float mk3 = (tv.y != tv.x) ? 1.f : 0.f;
  float mk5 = (tv.z != tv.y) ? 1.f : 0.f;
  float mk7 = (tv.w != tv.z) ? 1.f : 0.f;

  // stage blank column (8 KB) into LDS
#pragma unroll
  for (int j = 0; j < 8; ++j)
    g2l16(blb + j * 256 + lane * 4, &blanklds[j * 256]);

  uint2 pfA[16], pfB[16];
#pragma unroll
  for (int j = 0; j < 16; ++j) pfA[j] = eq[(size_t)j * 64];
  asm volatile("s_waitcnt vmcnt(0)" ::: "memory");     // one-time drain

  float a0 = (lane == 0) ? 1.f : 0.f;
  float a1 = 0, a2 = 0, a3 = 0, a4 = 0, a5 = 0, a6 = 0, a7 = 0, a8 = 0;
  int C = 0;        // per-lane block exponent (log2 units)
  int diffi = 0;    // C(lane-1) - C(lane), fixed between rescales

#define STEP32(BANK, J, TB) do {                                               \
    uint2 pv = pf##BANK[J];                                                    \
    float2 flo = __half22float2(*reinterpret_cast<const __half2*>(&pv.x));     \
    float2 fhi = __half22float2(*reinterpret_cast<const __half2*>(&pv.y));     \
    float pb = blanklds[(TB) + (J)];                                           \
    float h1 = ldexpf(dpp_shr1_f(a7), diffi);                                  \
    a8 = (a8 + a7) * pb;                                                       \
    a7 = (a7 + a6 + mk7 * a5) * fhi.y;                                         \
    a6 = (a6 + a5) * pb;                                                       \
    a5 = (a5 + a4 + mk5 * a3) * fhi.x;                                         \
    a4 = (a4 + a3) * pb;                                                       \
    a3 = (a3 + a2 + mk3 * a1) * flo.y;                                         \
    a2 = (a2 + a1) * pb;                                                       \
    a1 = (a1 + a0 + mk1 * h1) * flo.x;                                         \
    a0 = (a0 + h1) * pb;                                                       \
  } while (0)

  // Per-lane rescale with margin clamp (see header comment).
#define RESCALE8() do {                                                        \
    float mx = fmaxf(fmaxf(fmaxf(a0, a1), fmaxf(a2, a3)),                      \
                     fmaxf(fmaxf(a4, a5), fmaxf(fmaxf(a6, a7), a8)));          \
    bool live_ = (mx > 0.f);                                                   \
    int e_  = (int)((__float_as_uint(mx) >> 23) & 0xff);                       \
    int Cl_ = C + e_ - (127 + TGT_E);                                          \
    int key_ = live_ ? (Cl_ + KOFF) : 0;                                       \
    key_ = scanmax_i(key_);                                                    \
    int Cn_ = (key_ - KOFF) - MARG;                                            \
    if (live_ && Cl_ > Cn_) Cn_ = Cl_;                                         \
    int shE_ = Cn_ - C;                                                        \
    a0 = ldexpf(a0, -shE_); a1 = ldexpf(a1, -shE_); a2 = ldexpf(a2, -shE_);    \
    a3 = ldexpf(a3, -shE_); a4 = ldexpf(a4, -shE_); a5 = ldexpf(a5, -shE_);    \
    a6 = ldexpf(a6, -shE_); a7 = ldexpf(a7, -shE_); a8 = ldexpf(a8, -shE_);    \
    C = Cn_;                                                                   \
    diffi = dpp_shr1_i(C) - C;                                                 \
  } while (0)

#define ISSUE16(BANK, TBN) do {                                                \
    const uint2* p_ = eq + (size_t)(TBN) * 64;                                 \
    _Pragma("unroll")                                                          \
    for (int j_ = 0; j_ < 16; ++j_) pf##BANK[j_] = p_[(size_t)j_ * 64];        \
  } while (0)

#define BLK16(CUR, NXT, TB) do {                                               \
    int tbn_ = (TB) + 16; if (tbn_ > TT - 16) tbn_ = TT - 16;                  \
    ISSUE16(NXT, tbn_);                                                        \
    asm volatile("s_waitcnt vmcnt(16)" ::: "memory");                          \
    STEP32(CUR, 0, (TB));  STEP32(CUR, 1, (TB));  STEP32(CUR, 2, (TB));        \
    STEP32(CUR, 3, (TB));  STEP32(CUR, 4, (TB));  STEP32(CUR, 5, (TB));        \
    STEP32(CUR, 6, (TB));  STEP32(CUR, 7, (TB));                               \
    RESCALE8();                                                                \
    STEP32(CUR, 8, (TB));  STEP32(CUR, 9, (TB));  STEP32(CUR, 10, (TB));       \
    STEP32(CUR, 11, (TB)); STEP32(CUR, 12, (TB)); STEP32(CUR, 13, (TB));       \
    STEP32(CUR, 14, (TB)); STEP32(CUR, 15, (TB));                              \
    RESCALE8();                                                                \
  } while (0)

  int tcur = 0;
  for (int g = 0; g < TT / 32 && tcur + 32 <= len; ++g) {
    BLK16(A, B, tcur);
    BLK16(B, A, tcur + 16);
    tcur += 32;
  }

  // generic tail (len not a multiple of 32; not hit for this shape)
  if (tcur < len) {
    asm volatile("s_waitcnt vmcnt(0)" ::: "memory");
    while (tcur < len) {
      uint2 pv = eq[(size_t)tcur * 64];
      float2 flo = __half22float2(*reinterpret_cast<const __half2*>(&pv.x));
      float2 fhi = __half22float2(*reinterpret_cast<const __half2*>(&pv.y));
      float pb = blanklds[tcur];
      float h1 = ldexpf(dpp_shr1_f(a7), diffi);
      a8 = (a8 + a7) * pb;
      a7 = (a7 + a6 + mk7 * a5) * fhi.y;
      a6 = (a6 + a5) * pb;
      a5 = (a5 + a4 + mk5 * a3) * fhi.x;
      a4 = (a4 + a3) * pb;
      a3 = (a3 + a2 + mk3 * a1) * flo.y;
      a2 = (a2 + a1) * pb;
      a1 = (a1 + a0 + mk1 * h1) * flo.x;
      a0 = (a0 + h1) * pb;
      ++tcur;
      if ((tcur & 7) == 0) RESCALE8();
    }
  }

  // normalization constant: sum of -log2(Z_t) over t < len
  float dsm = 0.f;
  for (int k2 = 0; k2 < TT / 64; ++k2) {
    int t2 = lane + 64 * k2;
    if (t2 < len) dsm += d2b[t2];
  }
  dsm += __shfl_xor(dsm, 1);
  dsm += __shfl_xor(dsm, 2);
  dsm += __shfl_xor(dsm, 4);
  dsm += __shfl_xor(dsm, 8);
  dsm += __shfl_xor(dsm, 16);
  dsm += __shfl_xor(dsm, 32);

  afin[8 * lane + 0] = a0; afin[8 * lane + 1] = a1;
  afin[8 * lane + 2] = a2; afin[8 * lane + 3] = a3;
  afin[8 * lane + 4] = a4; afin[8 * lane + 5] = a5;
  afin[8 * lane + 6] = a6; afin[8 * lane + 7] = a7;
  if (lane == 63) afin[512] = a8;
  cfinl[lane] = C;
  __syncthreads();
  if (lane == 0) {
    int s1 = 2 * tl, s2 = 2 * tl - 1;
    float v1 = afin[s1], v2 = afin[s2];
    int C1 = cfinl[s1 >= 512 ? 63 : (s1 >> 3)];
    int C2 = cfinl[s2 >= 512 ? 63 : (s2 >> 3)];
    float l1 = (v1 > 0.f) ? (log2_fast(v1) + (float)C1) : -1e30f;
    float l2 = (v2 > 0.f) ? (log2_fast(v2) + (float)C2) : -1e30f;
    float m  = fmaxf(l1, l2);
    float r  = m + log2_fast(exp2_fast(l1 - m) + exp2_fast(l2 - m));
    lossw[b] = -F_LN2 * (r + dsm);
  }
#undef STEP32
#undef RESCALE8
#undef ISSUE16
#undef BLK16
}

// ---------------- zero_infinity guard, /tl, mean ----------------
__global__ __launch_bounds__(64) void k_final(const float* __restrict__ lossw,
                                              const int* __restrict__ tlen,
                                              float* __restrict__ out) {
  int i = threadIdx.x;
  float v = lossw[i];
  float d = (float)tlen[i];
  v = (v < 1e29f && v > -1e30f) ? (v / d) : 0.f;
  v += __shfl_xor(v, 1);
  v += __shfl_xor(v, 2);
  v += __shfl_xor(v, 4);
  v += __shfl_xor(v, 8);
  v += __shfl_xor(v, 16);
  v += __shfl_xor(v, 32);
  if (i == 0) out[0] = v * (1.f / BB);
}

extern "C" void kernel_launch(void* const* d_in, const int* in_sizes, int n_in,
                              void* d_out, int out_size, void* d_ws, size_t ws_size,
                              hipStream_t stream) {
  const float* lp = (const float*)d_in[0];
  const int* tgt  = (const int*)d_in[1];
  const int* ilen = (const int*)d_in[2];
  const int* tlen = (const int*)d_in[3];

  size_t eg_bytes = (size_t)BB * TT * SS * 2;          // 64 MB
  __half* Eg   = (__half*)d_ws;
  float* Bl    = (float*)((char*)d_ws + eg_bytes);     // [B][T]
  float* D2T   = Bl + (size_t)BB * TT;                 // [B][T]
  float* lossw = D2T + (size_t)BB * TT;                // [B]

  k_prep2<<<BB * (TT / 4), 256, 0, stream>>>(lp, tgt, Eg, Bl, D2T);
  k_ctc6<<<BB, 64, 0, stream>>>(Eg, Bl, tgt, ilen, tlen, D2T, lossw);
  k_final<<<1, 64, 0, stream>>>(lossw, tlen, (float*)d_out);
}

// Round 10
// 165.334 us; speedup vs baseline: 1.0160x; 1.0160x over previous
//
#include <hip/hip_runtime.h>
#include <hip/hip_fp16.h>
#include <stdint.h>

// Problem constants (fixed by setup_inputs)
#define TT 2048
#define BB 64
#define VV 256
#define SS 256
#define LL 513

#define F_L2E 1.4426950408889634f
#define F_LN2 0.6931471805599453f
#define TGT_E 40   // per-lane rescale target: lane max -> [2^40, 2^41)
#define MARG  50   // max allowed C(i-1)-C(i): bounds handoff to 2^(41+MARG)
#define KOFF  262144

static __device__ __forceinline__ float exp2_fast(float x) {
  float r; asm("v_exp_f32 %0, %1" : "=v"(r) : "v"(x)); return r;
}
static __device__ __forceinline__ float log2_fast(float x) {
  float r; asm("v_log_f32 %0, %1" : "=v"(r) : "v"(x)); return r;
}
static __device__ __forceinline__ void g2l16(const void* g, void* l) {
  __builtin_amdgcn_global_load_lds((const __attribute__((address_space(1))) void*)g,
                                   (__attribute__((address_space(3))) void*)l, 16, 0, 0);
}
// wave_shr:1 — lane i gets lane i-1's value; lane 0 gets 0 (bound_ctrl). Pure VALU.
static __device__ __forceinline__ float dpp_shr1_f(float x) {
  int r = __builtin_amdgcn_update_dpp(0, __float_as_int(x), 0x138, 0xF, 0xF, true);
  return __int_as_float(r);
}
static __device__ __forceinline__ int dpp_shr1_i(int x) {
  return __builtin_amdgcn_update_dpp(0, x, 0x138, 0xF, 0xF, true);
}
// One step of wave64 inclusive MAX-scan. shr1,2,4,8 (rmask F) then
// bcast15 (rmask 0xa) and bcast31 (rmask 0xc).
template <int CTRL, int RMASK>
static __device__ __forceinline__ int dppmax_i(int v) {
  int d = __builtin_amdgcn_update_dpp(v, v, CTRL, RMASK, 0xF, false);
  return v > d ? v : d;
}
static __device__ __forceinline__ int scanmax_i(int v) {
  v = dppmax_i<0x111, 0xF>(v);
  v = dppmax_i<0x112, 0xF>(v);
  v = dppmax_i<0x114, 0xF>(v);
  v = dppmax_i<0x118, 0xF>(v);
  v = dppmax_i<0x142, 0xa>(v);
  v = dppmax_i<0x143, 0xc>(v);
  return v;   // inclusive prefix max per lane
}

// ---------------------------------------------------------------------
// Phase 1: fused exp + row-sum + target-gather. (unchanged, at BW floor)
// ---------------------------------------------------------------------
__global__ __launch_bounds__(256) void k_prep2(const float* __restrict__ lp,
                                               const int* __restrict__ tgt,
                                               __half* __restrict__ Eg,
                                               float* __restrict__ Bl,
                                               float* __restrict__ D2T) {
  __shared__ int tgtl[SS];
  __shared__ __half elds[4][VV];
  int b  = blockIdx.x & (BB - 1);
  int t0 = (blockIdx.x >> 6) << 2;
  int tid = threadIdx.x;
  tgtl[tid] = tgt[b * SS + tid];
  __syncthreads();
  int w = tid >> 6, lane = tid & 63;
  int t = t0 + w;
  float4 x = reinterpret_cast<const float4*>(lp + ((size_t)t * BB + b) * VV)[lane];
  float e0 = exp2_fast(x.x * F_L2E), e1 = exp2_fast(x.y * F_L2E);
  float e2 = exp2_fast(x.z * F_L2E), e3 = exp2_fast(x.w * F_L2E);
  float z = (e0 + e1) + (e2 + e3);
  z += __shfl_xor(z, 1);
  z += __shfl_xor(z, 2);
  z += __shfl_xor(z, 4);
  z += __shfl_xor(z, 8);
  z += __shfl_xor(z, 16);
  z += __shfl_xor(z, 32);
  elds[w][4 * lane + 0] = __float2half_rn(e0);
  elds[w][4 * lane + 1] = __float2half_rn(e1);
  elds[w][4 * lane + 2] = __float2half_rn(e2);
  elds[w][4 * lane + 3] = __float2half_rn(e3);
  asm volatile("s_waitcnt lgkmcnt(0)" ::: "memory");   // wave-local write->read
  int s = 4 * lane;
  union { __half h[4]; uint2 u; } pk;
  pk.h[0] = elds[w][tgtl[s + 0]];
  pk.h[1] = elds[w][tgtl[s + 1]];
  pk.h[2] = elds[w][tgtl[s + 2]];
  pk.h[3] = elds[w][tgtl[s + 3]];
  reinterpret_cast<uint2*>(Eg + ((size_t)b * TT + t) * SS)[lane] = pk.u;
  if (lane == 0) {
    Bl[(size_t)b * TT + t]  = e0;
    D2T[(size_t)b * TT + t] = -log2_fast(z);
  }
}

// ---------------------------------------------------------------------
// Phase 2: f32 CTC DP, per-lane block exponent with margin clamp (R9
// numerics, proven absmax 0.0). This round: triple-buffered prefetch
// (vmcnt(32), loads get ~2 blocks of slack) + blank probs batched into
// registers at block start (no per-step LDS on the critical path).
// ---------------------------------------------------------------------
__global__ __launch_bounds__(64) void k_ctc7(const __half* __restrict__ Eg,
                                             const float* __restrict__ Bl,
                                             const int* __restrict__ tgt,
                                             const int* __restrict__ ilen,
                                             const int* __restrict__ tlen,
                                             const float* __restrict__ D2T,
                                             float* __restrict__ lossw) {
  __shared__ float blanklds[TT];   // 8 KB
  __shared__ float afin[LL];
  __shared__ int   cfinl[64];
  int b = blockIdx.x, lane = threadIdx.x;
  int len = ilen[b]; if (len > TT) len = TT; if (len < 0) len = 0;
  int tl  = tlen[b]; if (tl > SS) tl = SS; if (tl < 1) tl = 1;

  const float* blb = Bl  + (size_t)b * TT;
  const float* d2b = D2T + (size_t)b * TT;
  const uint2* eq  = reinterpret_cast<const uint2*>(Eg) + (size_t)b * TT * 64 + lane;

  int4 tv = reinterpret_cast<const int4*>(tgt + b * SS)[lane];
  int pw  = __shfl_up(tv.w, 1);
  float mk1 = (lane > 0 && tv.x != pw) ? 1.f : 0.f;
  float mk3 = (tv.y != tv.x) ? 1.f : 0.f;
  float mk5 = (tv.z != tv.y) ? 1.f : 0.f;
  float mk7 = (tv.w != tv.z) ? 1.f : 0.f;

  // stage blank column (8 KB) into LDS
#pragma unroll
  for (int j = 0; j < 8; ++j)
    g2l16(blb + j * 256 + lane * 4, &blanklds[j * 256]);

  uint2 pfA[16], pfB[16], pfC[16];
  float a0 = (lane == 0) ? 1.f : 0.f;
  float a1 = 0, a2 = 0, a3 = 0, a4 = 0, a5 = 0, a6 = 0, a7 = 0, a8 = 0;
  int C = 0;        // per-lane block exponent (log2 units)
  int diffi = 0;    // C(lane-1) - C(lane), fixed between rescales

#define ISSUE16(BANK, TBN) do {                                                \
    const uint2* p_ = eq + (size_t)(TBN) * 64;                                 \
    _Pragma("unroll")                                                          \
    for (int j_ = 0; j_ < 16; ++j_) pf##BANK[j_] = p_[(size_t)j_ * 64];        \
  } while (0)

#define STEP32(BANK, J) do {                                                   \
    uint2 pv = pf##BANK[J];                                                    \
    float2 flo = __half22float2(*reinterpret_cast<const __half2*>(&pv.x));     \
    float2 fhi = __half22float2(*reinterpret_cast<const __half2*>(&pv.y));     \
    float pb = pbreg[J];                                                       \
    float h1 = ldexpf(dpp_shr1_f(a7), diffi);                                  \
    a8 = (a8 + a7) * pb;                                                       \
    a7 = (a7 + a6 + mk7 * a5) * fhi.y;                                         \
    a6 = (a6 + a5) * pb;                                                       \
    a5 = (a5 + a4 + mk5 * a3) * fhi.x;                                         \
    a4 = (a4 + a3) * pb;                                                       \
    a3 = (a3 + a2 + mk3 * a1) * flo.y;                                         \
    a2 = (a2 + a1) * pb;                                                       \
    a1 = (a1 + a0 + mk1 * h1) * flo.x;                                         \
    a0 = (a0 + h1) * pb;                                                       \
  } while (0)

  // Per-lane rescale with margin clamp (R9 numerics, unchanged).
#define RESCALE8() do {                                                        \
    float mx = fmaxf(fmaxf(fmaxf(a0, a1), fmaxf(a2, a3)),                      \
                     fmaxf(fmaxf(a4, a5), fmaxf(fmaxf(a6, a7), a8)));          \
    bool live_ = (mx > 0.f);                                                   \
    int e_  = (int)((__float_as_uint(mx) >> 23) & 0xff);                       \
    int Cl_ = C + e_ - (127 + TGT_E);                                          \
    int key_ = live_ ? (Cl_ + KOFF) : 0;                                       \
    key_ = scanmax_i(key_);                                                    \
    int Cn_ = (key_ - KOFF) - MARG;                                            \
    if (live_ && Cl_ > Cn_) Cn_ = Cl_;                                         \
    int shE_ = Cn_ - C;                                                        \
    a0 = ldexpf(a0, -shE_); a1 = ldexpf(a1, -shE_); a2 = ldexpf(a2, -shE_);    \
    a3 = ldexpf(a3, -shE_); a4 = ldexpf(a4, -shE_); a5 = ldexpf(a5, -shE_);    \
    a6 = ldexpf(a6, -shE_); a7 = ldexpf(a7, -shE_); a8 = ldexpf(a8, -shE_);    \
    C = Cn_;                                                                   \
    diffi = dpp_shr1_i(C) - C;                                                 \
  } while (0)

  // Compute bank CUR for 16 steps at TB; issue TB+32 into bank NXT first.
  // Steady state: 48 loads outstanding after issue; vmcnt(32) waits for
  // exactly the CUR bank's 16 (oldest), leaving 2 banks in flight.
#define BLK(CUR, NXT, TB, VMC) do {                                            \
    if ((VMC) == 32) ISSUE16(NXT, (TB) + 32);                                  \
    float pbreg[16];                                                           \
    _Pragma("unroll")                                                          \
    for (int j_ = 0; j_ < 16; ++j_) pbreg[j_] = blanklds[(TB) + j_];           \
    asm volatile("s_waitcnt vmcnt(%0)" :: "i"(VMC) : "memory");                \
    STEP32(CUR, 0);  STEP32(CUR, 1);  STEP32(CUR, 2);  STEP32(CUR, 3);         \
    STEP32(CUR, 4);  STEP32(CUR, 5);  STEP32(CUR, 6);  STEP32(CUR, 7);         \
    RESCALE8();                                                                \
    STEP32(CUR, 8);  STEP32(CUR, 9);  STEP32(CUR, 10); STEP32(CUR, 11);        \
    STEP32(CUR, 12); STEP32(CUR, 13); STEP32(CUR, 14); STEP32(CUR, 15);        \
    RESCALE8();                                                                \
  } while (0)

  int tcur = 0;
  if (len == TT) {
    ISSUE16(A, 0);
    ISSUE16(B, 16);
    // 128 blocks total: 42 iterations x 3 + 2 tail blocks
    for (int g = 0; g < 42; ++g) {
      BLK(A, C, tcur, 32);
      BLK(B, A, tcur + 16, 32);
      BLK(C, B, tcur + 32, 32);
      tcur += 48;
    }
    // tcur = 2016: A holds 2016, B holds 2032
    BLK(A, C, tcur, 16);
    BLK(B, C, tcur + 16, 0);
    tcur = TT;
  }

  // generic path (len < TT): plain per-step loads, same numerics
  if (tcur < len) {
    asm volatile("s_waitcnt vmcnt(0)" ::: "memory");
    while (tcur < len) {
      uint2 pv = eq[(size_t)tcur * 64];
      float2 flo = __half22float2(*reinterpret_cast<const __half2*>(&pv.x));
      float2 fhi = __half22float2(*reinterpret_cast<const __half2*>(&pv.y));
      float pb = blanklds[tcur];
      float h1 = ldexpf(dpp_shr1_f(a7), diffi);
      a8 = (a8 + a7) * pb;
      a7 = (a7 + a6 + mk7 * a5) * fhi.y;
      a6 = (a6 + a5) * pb;
      a5 = (a5 + a4 + mk5 * a3) * fhi.x;
      a4 = (a4 + a3) * pb;
      a3 = (a3 + a2 + mk3 * a1) * flo.y;
      a2 = (a2 + a1) * pb;
      a1 = (a1 + a0 + mk1 * h1) * flo.x;
      a0 = (a0 + h1) * pb;
      ++tcur;
      if ((tcur & 7) == 0) {
        float mx = fmaxf(fmaxf(fmaxf(a0, a1), fmaxf(a2, a3)),
                         fmaxf(fmaxf(a4, a5), fmaxf(fmaxf(a6, a7), a8)));
        bool live_ = (mx > 0.f);
        int e_  = (int)((__float_as_uint(mx) >> 23) & 0xff);
        int Cl_ = C + e_ - (127 + TGT_E);
        int key_ = live_ ? (Cl_ + KOFF) : 0;
        key_ = scanmax_i(key_);
        int Cn_ = (key_ - KOFF) - MARG;
        if (live_ && Cl_ > Cn_) Cn_ = Cl_;
        int shE_ = Cn_ - C;
        a0 = ldexpf(a0, -shE_); a1 = ldexpf(a1, -shE_); a2 = ldexpf(a2, -shE_);
        a3 = ldexpf(a3, -shE_); a4 = ldexpf(a4, -shE_); a5 = ldexpf(a5, -shE_);
        a6 = ldexpf(a6, -shE_); a7 = ldexpf(a7, -shE_); a8 = ldexpf(a8, -shE_);
        C = Cn_;
        diffi = dpp_shr1_i(C) - C;
      }
    }
  }

  // normalization constant: sum of -log2(Z_t) over t < len
  float dsm = 0.f;
  for (int k2 = 0; k2 < TT / 64; ++k2) {
    int t2 = lane + 64 * k2;
    if (t2 < len) dsm += d2b[t2];
  }
  dsm += __shfl_xor(dsm, 1);
  dsm += __shfl_xor(dsm, 2);
  dsm += __shfl_xor(dsm, 4);
  dsm += __shfl_xor(dsm, 8);
  dsm += __shfl_xor(dsm, 16);
  dsm += __shfl_xor(dsm, 32);

  afin[8 * lane + 0] = a0; afin[8 * lane + 1] = a1;
  afin[8 * lane + 2] = a2; afin[8 * lane + 3] = a3;
  afin[8 * lane + 4] = a4; afin[8 * lane + 5] = a5;
  afin[8 * lane + 6] = a6; afin[8 * lane + 7] = a7;
  if (lane == 63) afin[512] = a8;
  cfinl[lane] = C;
  __syncthreads();
  if (lane == 0) {
    int s1 = 2 * tl, s2 = 2 * tl - 1;
    float v1 = afin[s1], v2 = afin[s2];
    int C1 = cfinl[s1 >= 512 ? 63 : (s1 >> 3)];
    int C2 = cfinl[s2 >= 512 ? 63 : (s2 >> 3)];
    float l1 = (v1 > 0.f) ? (log2_fast(v1) + (float)C1) : -1e30f;
    float l2 = (v2 > 0.f) ? (log2_fast(v2) + (float)C2) : -1e30f;
    float m  = fmaxf(l1, l2);
    float r  = m + log2_fast(exp2_fast(l1 - m) + exp2_fast(l2 - m));
    lossw[b] = -F_LN2 * (r + dsm);
  }
#undef STEP32
#undef RESCALE8
#undef ISSUE16
#undef BLK
}

// ---------------- zero_infinity guard, /tl, mean ----------------
__global__ __launch_bounds__(64) void k_final(const float* __restrict__ lossw,
                                              const int* __restrict__ tlen,
                                              float* __restrict__ out) {
  int i = threadIdx.x;
  float v = lossw[i];
  float d = (float)tlen[i];
  v = (v < 1e29f && v > -1e30f) ? (v / d) : 0.f;
  v += __shfl_xor(v, 1);
  v += __shfl_xor(v, 2);
  v += __shfl_xor(v, 4);
  v += __shfl_xor(v, 8);
  v += __shfl_xor(v, 16);
  v += __shfl_xor(v, 32);
  if (i == 0) out[0] = v * (1.f / BB);
}

extern "C" void kernel_launch(void* const* d_in, const int* in_sizes, int n_in,
                              void* d_out, int out_size, void* d_ws, size_t ws_size,
                              hipStream_t stream) {
  const float* lp = (const float*)d_in[0];
  const int* tgt  = (const int*)d_in[1];
  const int* ilen = (const int*)d_in[2];
  const int* tlen = (const int*)d_in[3];

  size_t eg_bytes = (size_t)BB * TT * SS * 2;          // 64 MB
  __half* Eg   = (__half*)d_ws;
  float* Bl    = (float*)((char*)d_ws + eg_bytes);     // [B][T]
  float* D2T   = Bl + (size_t)BB * TT;                 // [B][T]
  float* lossw = D2T + (size_t)BB * TT;                // [B]

  k_prep2<<<BB * (TT / 4), 256, 0, stream>>>(lp, tgt, Eg, Bl, D2T);
  k_ctc7<<<BB, 64, 0, stream>>>(Eg, Bl, tgt, ilen, tlen, D2T, lossw);
  k_final<<<1, 64, 0, stream>>>(lossw, tlen, (float*)d_out);
}